// Round 1
// baseline (251.279 us; speedup 1.0000x reference)
//
#include <hip/hip_runtime.h>
#include <hip/hip_fp16.h>

// ---------------------------------------------------------------------------
// SoftDecisionTreeEnsemble: N_TREES=15, DEPTH=3, INPUT_DIM=128, N_CLASSES=10
// Strategy: memory-bound streaming of x (134 MB). Main GEMM z = x @ W^T
// ([B,128]x[128,105]) on f16 MFMA 16x16x32 (fp32 VALU would be 45us vs 23us
// memory floor). Param-only softmaxes folded into wlc[t][l][c] by prep kernel.
// ---------------------------------------------------------------------------

typedef float  f32x4 __attribute__((ext_vector_type(4)));
typedef _Float16 half8 __attribute__((ext_vector_type(8)));

#define TREES      15
#define IDIM       128
#define NCLS       10
#define NINT       7
#define NLVS       8
#define PER_TREE   (NINT*IDIM + NINT + NLVS*NCLS)   // 983
#define NODES      (TREES*NINT)                     // 105
#define NPAD       112                              // 7 n-tiles of 16
#define STR        113                              // LDS row stride (halves), odd to spread banks
#define MROWS      128                              // rows per block
#define WLC_N      (TREES*NLVS*NCLS)                // 1200

// ---------------------------------------------------------------------------
// Kernel 1: parameter preprocessing (runs every launch; ws is re-poisoned).
//   wq  [NPAD][128] fp16 : row g=7t+n is split_w[t][n][:]; rows 105..111 = 0
//   bq  [NPAD] fp32      : split_b, padded with 0
//   wlc [15][8][10] fp32 : softmax(leaf_logits) * softmax(tree_w)[t]
// ---------------------------------------------------------------------------
__global__ __launch_bounds__(256) void prep_kernel(const float* __restrict__ p,
                                                   __half* __restrict__ wq,
                                                   float* __restrict__ bq,
                                                   float* __restrict__ wlc) {
    int tid = threadIdx.x;
    // weights -> fp16 (RTN), zero-pad rows 105..111
    for (int i = tid; i < NPAD * IDIM; i += 256) {
        int g = i >> 7, k = i & 127;
        float v = 0.f;
        if (g < NODES) {
            int t = g / NINT, n = g % NINT;
            v = p[t * PER_TREE + n * IDIM + k];
        }
        wq[i] = __float2half(v);
    }
    // biases
    for (int i = tid; i < NPAD; i += 256) {
        float v = 0.f;
        if (i < NODES) {
            int t = i / NINT, n = i % NINT;
            v = p[t * PER_TREE + NINT * IDIM + n];
        }
        bq[i] = v;
    }
    // wlc[t][l][c] = softmax_c(leaf_logits[t][l][:]) * softmax(tree_w)[t]
    const float* tl = p + TREES * PER_TREE;  // 15 tree-weight logits
    for (int i = tid; i < WLC_N; i += 256) {
        int t = i / (NLVS * NCLS);
        int l = (i / NCLS) % NLVS;
        int c = i % NCLS;
        const float* ll = p + t * PER_TREE + NINT * IDIM + NINT + l * NCLS;
        float mx = ll[0];
        #pragma unroll
        for (int j = 1; j < NCLS; ++j) mx = fmaxf(mx, ll[j]);
        float se = 0.f;
        #pragma unroll
        for (int j = 0; j < NCLS; ++j) se += __expf(ll[j] - mx);
        float lsm = __expf(ll[c] - mx) / se;

        float m2 = tl[0];
        #pragma unroll
        for (int j = 1; j < TREES; ++j) m2 = fmaxf(m2, tl[j]);
        float s2 = 0.f;
        #pragma unroll
        for (int j = 0; j < TREES; ++j) s2 += __expf(tl[j] - m2);
        float tw = __expf(tl[t] - m2) / s2;

        wlc[i] = lsm * tw;
    }
}

// ---------------------------------------------------------------------------
// Kernel 2: fused main kernel. 256 threads (4 waves), 128 rows per block.
// Wave w owns n-tiles {w, w+4} (wave 3: just tile 3). B-frags in registers.
// A-frags loaded straight from global fp32 -> cvt fp16 (16 rows x 128B
// contiguous per wave-instruction -> fully coalesced).
// ---------------------------------------------------------------------------
__global__ __launch_bounds__(256, 4) void tree_main(const float* __restrict__ x,
                                                    const __half* __restrict__ wq,
                                                    const float* __restrict__ bq,
                                                    const float* __restrict__ wlc,
                                                    float* __restrict__ out) {
    __shared__ __half s_sh[MROWS * STR];     // sigmoid values, fp16
    __shared__ float  wlc_sh[WLC_N];
    __shared__ float  out_sh[MROWS * NCLS];

    const int tid  = threadIdx.x;
    const int lane = tid & 63;
    const int wave = tid >> 6;
    const int lm   = lane & 15;   // row-in-tile (A) / col-in-tile (B,C)
    const int lq   = lane >> 4;   // quad

    for (int i = tid; i < WLC_N; i += 256) wlc_sh[i] = wlc[i];

    // --- B fragments (weights), loaded once ---
    // B[k][n] = wq[n_global][k]; lane holds n=lm, k = 32*s + 8*lq + j
    const int T0 = wave;
    const int T1 = wave + 4;
    const bool two = (T1 < 7);
    half8 bf0[4], bf1[4];
    float bb0, bb1 = 0.f;
    bb0 = bq[16 * T0 + lm];
    #pragma unroll
    for (int s = 0; s < 4; ++s)
        bf0[s] = *reinterpret_cast<const half8*>(wq + (16 * T0 + lm) * IDIM + 32 * s + 8 * lq);
    if (two) {
        bb1 = bq[16 * T1 + lm];
        #pragma unroll
        for (int s = 0; s < 4; ++s)
            bf1[s] = *reinterpret_cast<const half8*>(wq + (16 * T1 + lm) * IDIM + 32 * s + 8 * lq);
    }

    const long base_row = (long)blockIdx.x * MROWS;

    // --- main GEMM + sigmoid, 8 m-tiles of 16 rows ---
    for (int mt = 0; mt < 8; ++mt) {
        const float* xr = x + (base_row + mt * 16 + lm) * IDIM + 8 * lq;
        half8 af[4];
        #pragma unroll
        for (int s = 0; s < 4; ++s) {
            f32x4 f0 = *reinterpret_cast<const f32x4*>(xr + 32 * s);
            f32x4 f1 = *reinterpret_cast<const f32x4*>(xr + 32 * s + 4);
            half8 a;
            #pragma unroll
            for (int j = 0; j < 4; ++j) {
                a[j]     = (_Float16)f0[j];
                a[j + 4] = (_Float16)f1[j];
            }
            af[s] = a;
        }

        f32x4 acc0 = {0.f, 0.f, 0.f, 0.f};
        #pragma unroll
        for (int s = 0; s < 4; ++s)
            acc0 = __builtin_amdgcn_mfma_f32_16x16x32_f16(af[s], bf0[s], acc0, 0, 0, 0);
        {
            const int colbase = 16 * T0 + lm;
            #pragma unroll
            for (int r = 0; r < 4; ++r) {
                float z = acc0[r] + bb0;                    // C/D: row = lq*4+r, col = lm
                float sg = 1.0f / (1.0f + __expf(-z));
                s_sh[(mt * 16 + lq * 4 + r) * STR + colbase] = __float2half(sg);
            }
        }
        if (two) {
            f32x4 acc1 = {0.f, 0.f, 0.f, 0.f};
            #pragma unroll
            for (int s = 0; s < 4; ++s)
                acc1 = __builtin_amdgcn_mfma_f32_16x16x32_f16(af[s], bf1[s], acc1, 0, 0, 0);
            const int colbase = 16 * T1 + lm;
            #pragma unroll
            for (int r = 0; r < 4; ++r) {
                float z = acc1[r] + bb1;
                float sg = 1.0f / (1.0f + __expf(-z));
                s_sh[(mt * 16 + lq * 4 + r) * STR + colbase] = __float2half(sg);
            }
        }
    }
    __syncthreads();

    // --- postprocess: 2 threads per row (h=0: trees 0..7, h=1: trees 8..14) ---
    const int row = tid >> 1;
    const int h   = tid & 1;
    const __half* sr = s_sh + row * STR;
    float acc[NCLS];
    #pragma unroll
    for (int c = 0; c < NCLS; ++c) acc[c] = 0.f;

    const int t_beg = h ? 8 : 0;
    const int t_end = h ? 15 : 8;
    for (int t = t_beg; t < t_end; ++t) {
        const __half* sn = sr + t * NINT;
        float s0 = __half2float(sn[0]);
        float s1 = __half2float(sn[1]);
        float s2 = __half2float(sn[2]);
        float s3 = __half2float(sn[3]);
        float s4 = __half2float(sn[4]);
        float s5 = __half2float(sn[5]);
        float s6 = __half2float(sn[6]);
        // node tree: leaf l -> factors: root s0 (p if l>=4), level1 s1/s2
        // (p if (l>>1)&1), level2 s[3+(l>>1)] (p if l&1)
        float u1 = 1.f - s0, u2 = s0;
        float q1 = u1 * s1, q0 = u1 - q1;   // leaves 0-1 / 2-3
        float q3 = u2 * s2, q2 = u2 - q3;   // leaves 4-5 / 6-7
        float L1 = q0 * s3, L0 = q0 - L1;
        float L3 = q1 * s4, L2 = q1 - L3;
        float L5 = q2 * s5, L4 = q2 - L5;
        float L7 = q3 * s6, L6 = q3 - L7;
        const float* wl = wlc_sh + t * (NLVS * NCLS);
        #pragma unroll
        for (int c = 0; c < NCLS; ++c) {
            float a = L0 * wl[c]       + L1 * wl[NCLS + c]
                    + L2 * wl[2*NCLS+c] + L3 * wl[3*NCLS+c]
                    + L4 * wl[4*NCLS+c] + L5 * wl[5*NCLS+c]
                    + L6 * wl[6*NCLS+c] + L7 * wl[7*NCLS+c];
            acc[c] += a;
        }
    }
    // combine the two half-sums (lanes tid, tid^1 are in the same wave)
    #pragma unroll
    for (int c = 0; c < NCLS; ++c) acc[c] += __shfl_xor(acc[c], 1, 64);
    if (!h) {
        #pragma unroll
        for (int c = 0; c < NCLS; ++c) out_sh[row * NCLS + c] = acc[c];
    }
    __syncthreads();

    // coalesced block write
    const long ob = (long)blockIdx.x * (MROWS * NCLS);
    for (int i = tid; i < MROWS * NCLS; i += 256) out[ob + i] = out_sh[i];
}

// ---------------------------------------------------------------------------
extern "C" void kernel_launch(void* const* d_in, const int* in_sizes, int n_in,
                              void* d_out, int out_size, void* d_ws, size_t ws_size,
                              hipStream_t stream) {
    const float* x      = (const float*)d_in[0];
    const float* params = (const float*)d_in[1];
    float* out = (float*)d_out;

    __half* wq  = (__half*)d_ws;                              // 112*128 halves = 28672 B
    float*  bq  = (float*)((char*)d_ws + NPAD * IDIM * 2);    // 448 B
    float*  wlc = bq + NPAD;                                  // 4800 B

    const int batch  = in_sizes[0] / IDIM;     // 262144
    const int blocks = batch / MROWS;          // 2048

    prep_kernel<<<1, 256, 0, stream>>>(params, wq, bq, wlc);
    tree_main<<<blocks, 256, 0, stream>>>(x, wq, bq, wlc, out);
}

// Round 2
// 221.594 us; speedup vs baseline: 1.1340x; 1.1340x over previous
//
#include <hip/hip_runtime.h>
#include <hip/hip_fp16.h>

// ---------------------------------------------------------------------------
// SoftDecisionTreeEnsemble: N_TREES=15, DEPTH=3, INPUT_DIM=128, N_CLASSES=10
// R1: replace scalar leaf->class contraction (600 ds_read_b32/thread, LDS-pipe
// bound at ~50us) with a second MFMA GEMM: leaf_probs[128,128pad] x wbT[128,16].
// Single reused LDS buffer [128][136] halves (34.8KB -> 4 blocks/CU).
// ---------------------------------------------------------------------------

typedef float    f32x4 __attribute__((ext_vector_type(4)));
typedef _Float16 half8 __attribute__((ext_vector_type(8)));

#define TREES      15
#define IDIM       128
#define NCLS       10
#define NINT       7
#define NLVS       8
#define PER_TREE   (NINT*IDIM + NINT + NLVS*NCLS)   // 983
#define NODES      (TREES*NINT)                     // 105
#define NPAD       112                              // 7 n-tiles of 16
#define MROWS      128                              // rows per block
#define LSTR       136                              // LDS row stride (halves); 272B = 16B-aligned rows
#define KPAD       128                              // leaf K padded to 4 MFMA steps

// ---------------------------------------------------------------------------
// prep: wq[112][128] f16 (split_w rows g=7t+n, zero-padded), bq[112] f32,
//       wbT[16][128] f16: wbT[c][k] = softmax(leaf_logits[t][l])[c] *
//                                     softmax(tree_w)[t],  k = 8t+l, else 0.
// ---------------------------------------------------------------------------
__global__ __launch_bounds__(256) void prep_kernel(const float* __restrict__ p,
                                                   _Float16* __restrict__ wq,
                                                   float* __restrict__ bq,
                                                   _Float16* __restrict__ wbT) {
    const int gid = blockIdx.x * 256 + threadIdx.x;   // 2048 threads
    const int nthr = gridDim.x * 256;

    for (int i = gid; i < NPAD * IDIM; i += nthr) {
        int g = i >> 7, k = i & 127;
        float v = 0.f;
        if (g < NODES) {
            int t = g / NINT, n = g % NINT;
            v = p[t * PER_TREE + n * IDIM + k];
        }
        wq[i] = (_Float16)v;
    }
    for (int i = gid; i < NPAD; i += nthr) {
        float v = 0.f;
        if (i < NODES) {
            int t = i / NINT, n = i % NINT;
            v = p[t * PER_TREE + NINT * IDIM + n];
        }
        bq[i] = v;
    }
    const float* tl = p + TREES * PER_TREE;  // 15 tree-weight logits
    for (int i = gid; i < 16 * KPAD; i += nthr) {
        int c = i >> 7, k = i & 127;
        float v = 0.f;
        if (c < NCLS && k < TREES * NLVS) {
            int t = k >> 3, l = k & 7;
            const float* ll = p + t * PER_TREE + NINT * IDIM + NINT + l * NCLS;
            float mx = ll[0];
            #pragma unroll
            for (int j = 1; j < NCLS; ++j) mx = fmaxf(mx, ll[j]);
            float se = 0.f;
            #pragma unroll
            for (int j = 0; j < NCLS; ++j) se += __expf(ll[j] - mx);
            float lsm = __expf(ll[c] - mx) / se;

            float m2 = tl[0];
            #pragma unroll
            for (int j = 1; j < TREES; ++j) m2 = fmaxf(m2, tl[j]);
            float s2 = 0.f;
            #pragma unroll
            for (int j = 0; j < TREES; ++j) s2 += __expf(tl[j] - m2);
            float tw = __expf(tl[t] - m2) / s2;
            v = lsm * tw;
        }
        wbT[i] = (_Float16)v;
    }
}

// ---------------------------------------------------------------------------
// main kernel: 256 threads (4 waves), 128 rows per block.
// A: z-GEMM (f16 MFMA) + sigmoid -> s_sh cols 0..104
// B: per row-half leaf products (regs) -> overwrite s_sh as leaf k=0..127
// C: MFMA [128,128]x[128,16] vs wbT -> scatter-store out
// ---------------------------------------------------------------------------
__global__ __launch_bounds__(256, 4) void tree_main(const float* __restrict__ x,
                                                    const _Float16* __restrict__ wq,
                                                    const float* __restrict__ bq,
                                                    const _Float16* __restrict__ wbT,
                                                    float* __restrict__ out) {
    __shared__ _Float16 s_sh[MROWS * LSTR];   // 34816 B

    const int tid  = threadIdx.x;
    const int lane = tid & 63;
    const int wave = tid >> 6;
    const int lm   = lane & 15;   // row-in-tile (A) / col-in-tile (B,C)
    const int lq   = lane >> 4;   // quad

    // --- B fragments (split weights): wave w owns n-tiles {w, w+4} ---
    const int T0 = wave;
    const int T1 = wave + 4;
    const bool two = (T1 < 7);
    half8 bf0[4], bf1[4];
    float bb0 = bq[16 * T0 + lm];
    float bb1 = two ? bq[16 * T1 + lm] : 0.f;
    #pragma unroll
    for (int s = 0; s < 4; ++s)
        bf0[s] = *reinterpret_cast<const half8*>(wq + (16 * T0 + lm) * IDIM + 32 * s + 8 * lq);
    if (two) {
        #pragma unroll
        for (int s = 0; s < 4; ++s)
            bf1[s] = *reinterpret_cast<const half8*>(wq + (16 * T1 + lm) * IDIM + 32 * s + 8 * lq);
    }

    const long base_row = (long)blockIdx.x * MROWS;

    // ---------------- Phase A: z-GEMM + sigmoid ----------------
    for (int mt = 0; mt < 8; ++mt) {
        const float* xr = x + (base_row + mt * 16 + lm) * IDIM + 8 * lq;
        half8 af[4];
        #pragma unroll
        for (int s = 0; s < 4; ++s) {
            f32x4 f0 = *reinterpret_cast<const f32x4*>(xr + 32 * s);
            f32x4 f1 = *reinterpret_cast<const f32x4*>(xr + 32 * s + 4);
            half8 a;
            #pragma unroll
            for (int j = 0; j < 4; ++j) {
                a[j]     = (_Float16)f0[j];
                a[j + 4] = (_Float16)f1[j];
            }
            af[s] = a;
        }

        f32x4 acc0 = {0.f, 0.f, 0.f, 0.f};
        #pragma unroll
        for (int s = 0; s < 4; ++s)
            acc0 = __builtin_amdgcn_mfma_f32_16x16x32_f16(af[s], bf0[s], acc0, 0, 0, 0);
        {
            const int colbase = 16 * T0 + lm;
            #pragma unroll
            for (int r = 0; r < 4; ++r) {
                float z  = acc0[r] + bb0;                  // C/D: row=lq*4+r, col=lm
                float sg = __builtin_amdgcn_rcpf(1.0f + __expf(-z));
                s_sh[(mt * 16 + lq * 4 + r) * LSTR + colbase] = (_Float16)sg;
            }
        }
        if (two) {
            f32x4 acc1 = {0.f, 0.f, 0.f, 0.f};
            #pragma unroll
            for (int s = 0; s < 4; ++s)
                acc1 = __builtin_amdgcn_mfma_f32_16x16x32_f16(af[s], bf1[s], acc1, 0, 0, 0);
            const int colbase = 16 * T1 + lm;
            #pragma unroll
            for (int r = 0; r < 4; ++r) {
                float z  = acc1[r] + bb1;
                float sg = __builtin_amdgcn_rcpf(1.0f + __expf(-z));
                s_sh[(mt * 16 + lq * 4 + r) * LSTR + colbase] = (_Float16)sg;
            }
        }
    }
    __syncthreads();

    // ---------------- Phase B: leaf probabilities ----------------
    // h is wave-uniform (waves 0,1 -> trees 0..7; waves 2,3 -> trees 8..14).
    // Relative sigmoid col for tree tt (local) node n is 7*tt+n for both h
    // (h=1 base is col 56 = 7*8). Read all sigmoids into regs, barrier,
    // overwrite the same buffer with leaf values k=8t+l (fp16, zero-padded).
    {
        const int row = tid & 127;
        const int h   = tid >> 7;
        const _Float16* sr = s_sh + row * LSTR + 56 * h;
        half8 sv[8];
        #pragma unroll
        for (int j = 0; j < 8; ++j)
            sv[j] = *reinterpret_cast<const half8*>(sr + 8 * j);

        half8 leafv[8];
        #pragma unroll
        for (int tt = 0; tt < 8; ++tt) {
            if (h == 1 && tt == 7) {          // wave-uniform branch
                half8 zz = {(_Float16)0.f, (_Float16)0.f, (_Float16)0.f, (_Float16)0.f,
                            (_Float16)0.f, (_Float16)0.f, (_Float16)0.f, (_Float16)0.f};
                leafv[7] = zz;
            } else {
                float s0 = (float)sv[(7*tt+0) >> 3][(7*tt+0) & 7];
                float s1 = (float)sv[(7*tt+1) >> 3][(7*tt+1) & 7];
                float s2 = (float)sv[(7*tt+2) >> 3][(7*tt+2) & 7];
                float s3 = (float)sv[(7*tt+3) >> 3][(7*tt+3) & 7];
                float s4 = (float)sv[(7*tt+4) >> 3][(7*tt+4) & 7];
                float s5 = (float)sv[(7*tt+5) >> 3][(7*tt+5) & 7];
                float s6 = (float)sv[(7*tt+6) >> 3][(7*tt+6) & 7];
                float u1 = 1.f - s0, u2 = s0;
                float q1 = u1 * s1, q0 = u1 - q1;
                float q3 = u2 * s2, q2 = u2 - q3;
                float L1 = q0 * s3, L0 = q0 - L1;
                float L3 = q1 * s4, L2 = q1 - L3;
                float L5 = q2 * s5, L4 = q2 - L5;
                float L7 = q3 * s6, L6 = q3 - L7;
                half8 lv;
                lv[0] = (_Float16)L0; lv[1] = (_Float16)L1;
                lv[2] = (_Float16)L2; lv[3] = (_Float16)L3;
                lv[4] = (_Float16)L4; lv[5] = (_Float16)L5;
                lv[6] = (_Float16)L6; lv[7] = (_Float16)L7;
                leafv[tt] = lv;
            }
        }
        __syncthreads();   // all sigmoid reads done before any leaf overwrite
        _Float16* lw = s_sh + row * LSTR + 64 * h;
        #pragma unroll
        for (int j = 0; j < 8; ++j)
            *reinterpret_cast<half8*>(lw + 8 * j) = leafv[j];
    }
    __syncthreads();

    // ---------------- Phase C: leaf x wbT MFMA ----------------
    {
        half8 wbf[4];
        #pragma unroll
        for (int s = 0; s < 4; ++s)
            wbf[s] = *reinterpret_cast<const half8*>(wbT + lm * KPAD + 32 * s + 8 * lq);

        #pragma unroll
        for (int u = 0; u < 2; ++u) {
            const int mt = wave + 4 * u;
            half8 af[4];
            #pragma unroll
            for (int s = 0; s < 4; ++s)
                af[s] = *reinterpret_cast<const half8*>(s_sh + (16 * mt + lm) * LSTR + 32 * s + 8 * lq);
            f32x4 acc = {0.f, 0.f, 0.f, 0.f};
            #pragma unroll
            for (int s = 0; s < 4; ++s)
                acc = __builtin_amdgcn_mfma_f32_16x16x32_f16(af[s], wbf[s], acc, 0, 0, 0);
            if (lm < NCLS) {
                #pragma unroll
                for (int r = 0; r < 4; ++r)
                    out[(base_row + 16 * mt + 4 * lq + r) * NCLS + lm] = acc[r];
            }
        }
    }
}

// ---------------------------------------------------------------------------
extern "C" void kernel_launch(void* const* d_in, const int* in_sizes, int n_in,
                              void* d_out, int out_size, void* d_ws, size_t ws_size,
                              hipStream_t stream) {
    const float* x      = (const float*)d_in[0];
    const float* params = (const float*)d_in[1];
    float* out = (float*)d_out;

    _Float16* wq  = (_Float16*)d_ws;                             // 28672 B
    float*    bq  = (float*)((char*)d_ws + NPAD * IDIM * 2);     // 448 B
    _Float16* wbT = (_Float16*)((char*)bq + NPAD * 4);           // 4096 B

    const int batch  = in_sizes[0] / IDIM;     // 262144
    const int blocks = batch / MROWS;          // 2048

    prep_kernel<<<8, 256, 0, stream>>>(params, wq, bq, wbT);
    tree_main<<<blocks, 256, 0, stream>>>(x, wq, bq, wbT, out);
}

// Round 3
// 204.299 us; speedup vs baseline: 1.2300x; 1.0847x over previous
//
#include <hip/hip_runtime.h>
#include <hip/hip_fp16.h>

// ---------------------------------------------------------------------------
// SoftDecisionTreeEnsemble: N_TREES=15, DEPTH=3, INPUT_DIM=128, N_CLASSES=10
// R2: latency-bound fix. R1 had only 8 loads in flight/wave (2.6 B/cyc/CU by
// Little's law == measured). Now: persistent blocks (2/CU), double-buffered
// 32KB x-tiles staged via global_load_lds DMA (deep queue, no VGPRs), wave-
// private quarters (no barriers), B-frags resident across 8 tiles.
// x DMA uses per-row 16B-chunk rotation (swizzle on global source) so the
// fragment ds_read_b128 gather is bank-uniform.
// ---------------------------------------------------------------------------

typedef float    f32x4 __attribute__((ext_vector_type(4)));
typedef _Float16 half8 __attribute__((ext_vector_type(8)));

#define TREES      15
#define IDIM       128
#define NCLS       10
#define NINT       7
#define NLVS       8
#define PER_TREE   (NINT*IDIM + NINT + NLVS*NCLS)   // 983
#define NODES      (TREES*NINT)                     // 105
#define NPAD       112                              // 7 n-tiles of 16
#define KPAD       128                              // leaf K padded
#define RSTR       272                              // s/leaf row stride bytes (136 halves)
#define NBLK       512                              // 2 blocks/CU

// ---------------------------------------------------------------------------
// prep: wq[112][128] f16 (row g=7t+n, zero-padded), bq[112] f32 (zero-padded),
//       wbT[16][128] f16: wbT[c][8t+l] = softmax(leaf_logits[t][l])[c]*tw[t].
// Zero padding is load-bearing: padded nodes give z=0 -> sigmoid 0.5 ->
// garbage-free; padded leaf cols/classes contribute 0.
// ---------------------------------------------------------------------------
__global__ __launch_bounds__(256) void prep_kernel(const float* __restrict__ p,
                                                   _Float16* __restrict__ wq,
                                                   float* __restrict__ bq,
                                                   _Float16* __restrict__ wbT) {
    const int gid  = blockIdx.x * 256 + threadIdx.x;
    const int nthr = gridDim.x * 256;

    for (int i = gid; i < NPAD * IDIM; i += nthr) {
        int g = i >> 7, k = i & 127;
        float v = 0.f;
        if (g < NODES) {
            int t = g / NINT, n = g % NINT;
            v = p[t * PER_TREE + n * IDIM + k];
        }
        wq[i] = (_Float16)v;
    }
    for (int i = gid; i < NPAD; i += nthr) {
        float v = 0.f;
        if (i < NODES) {
            int t = i / NINT, n = i % NINT;
            v = p[t * PER_TREE + NINT * IDIM + n];
        }
        bq[i] = v;
    }
    const float* tl = p + TREES * PER_TREE;
    for (int i = gid; i < 16 * KPAD; i += nthr) {
        int c = i >> 7, k = i & 127;
        float v = 0.f;
        if (c < NCLS && k < TREES * NLVS) {
            int t = k >> 3, l = k & 7;
            const float* ll = p + t * PER_TREE + NINT * IDIM + NINT + l * NCLS;
            float mx = ll[0];
            #pragma unroll
            for (int j = 1; j < NCLS; ++j) mx = fmaxf(mx, ll[j]);
            float se = 0.f;
            #pragma unroll
            for (int j = 0; j < NCLS; ++j) se += __expf(ll[j] - mx);
            float lsm = __expf(ll[c] - mx) / se;

            float m2 = tl[0];
            #pragma unroll
            for (int j = 1; j < TREES; ++j) m2 = fmaxf(m2, tl[j]);
            float s2 = 0.f;
            #pragma unroll
            for (int j = 0; j < TREES; ++j) s2 += __expf(tl[j] - m2);
            float tw = __expf(tl[t] - m2) / s2;
            v = lsm * tw;
        }
        wbT[i] = (_Float16)v;
    }
}

// DMA one wave-quarter (16 rows x 512B) of an x tile into LDS, with per-row
// 16B-chunk rotation: row r chunk c16 stored at slot (c16 + r) & 31.
// LDS dest of global_load_lds is wave-uniform base + lane*16 (lane-linear),
// so the swizzle is applied on the *global source* side.
__device__ __forceinline__ void dma_quarter(const float* __restrict__ x,
                                            long grow0, char* qdst, int lane) {
    const int slot = lane & 31;
    #pragma unroll
    for (int it = 0; it < 8; ++it) {
        int r   = 2 * it + (lane >> 5);
        int c16 = (slot - r) & 31;
        const float* gp = x + (grow0 + r) * IDIM + c16 * 4;
        __builtin_amdgcn_global_load_lds(
            (const __attribute__((address_space(1))) void*)gp,
            (__attribute__((address_space(3))) void*)(qdst + it * 1024),
            16, 0, 0);
    }
}

// ---------------------------------------------------------------------------
__global__ __launch_bounds__(256, 2) void tree_main(const float* __restrict__ x,
                                                    const _Float16* __restrict__ wq,
                                                    const float* __restrict__ bq,
                                                    const _Float16* __restrict__ wbT,
                                                    float* __restrict__ out,
                                                    int tpb) {
    __shared__ __align__(16) char lds[2][32768];

    const int tid  = threadIdx.x;
    const int lane = tid & 63;
    const int w    = tid >> 6;        // wave id: owns rows 16w..16w+15 of tile
    const int lm   = lane & 15;
    const int lq   = lane >> 4;
    const int rg   = lane >> 2;       // Phase B row (0..15)
    const int g    = lane & 3;        // Phase B tree group

    const long tile0 = (long)blockIdx.x * tpb;

    // prime the pipeline: DMA tile 0
    dma_quarter(x, tile0 * 64 + 16 * w, &lds[0][w * 8192], lane);

    // resident weights: B-frags (7 n-tiles), biases, class weights
    half8 bf[7][4];
    float bb[7];
    #pragma unroll
    for (int nt = 0; nt < 7; ++nt) {
        bb[nt] = bq[16 * nt + lm];
        #pragma unroll
        for (int s = 0; s < 4; ++s)
            bf[nt][s] = *reinterpret_cast<const half8*>(wq + (16 * nt + lm) * IDIM + 32 * s + 8 * lq);
    }
    half8 wbf[4];
    #pragma unroll
    for (int s = 0; s < 4; ++s)
        wbf[s] = *reinterpret_cast<const half8*>(wbT + lm * KPAD + 32 * s + 8 * lq);

    for (int i = 0; i < tpb; ++i) {
        char* qcur = &lds[i & 1][w * 8192];
        const long grow = (tile0 + i) * 64;      // global row of this tile

        // wait for own DMA (wave-private; no barrier needed)
        asm volatile("" ::: "memory");
        __builtin_amdgcn_s_waitcnt(0x0F70);      // vmcnt(0), lgkm/exp free
        asm volatile("" ::: "memory");

        // ---- A-fragment gather from swizzled LDS + cvt to f16 ----
        half8 af[4];
        #pragma unroll
        for (int s = 0; s < 4; ++s) {
            int cc = 8 * s + 2 * lq;
            f32x4 f0 = *(const f32x4*)(qcur + lm * 512 + (((cc     + lm) & 31) << 4));
            f32x4 f1 = *(const f32x4*)(qcur + lm * 512 + (((cc + 1 + lm) & 31) << 4));
            half8 a;
            #pragma unroll
            for (int j = 0; j < 4; ++j) {
                a[j]     = (_Float16)f0[j];
                a[j + 4] = (_Float16)f1[j];
            }
            af[s] = a;
        }

        // kick off next tile's DMA into the other buffer
        if (i + 1 < tpb)
            dma_quarter(x, (tile0 + i + 1) * 64 + 16 * w, &lds[(i + 1) & 1][w * 8192], lane);

        // ---- Phase A: z-GEMM + sigmoid -> packed cols 8t+n ----
        #pragma unroll
        for (int nt = 0; nt < 7; ++nt) {
            f32x4 acc = {0.f, 0.f, 0.f, 0.f};
            #pragma unroll
            for (int s = 0; s < 4; ++s)
                acc = __builtin_amdgcn_mfma_f32_16x16x32_f16(af[s], bf[nt][s], acc, 0, 0, 0);
            int node = 16 * nt + lm;
            int col  = node + ((node * 9363) >> 16);   // node + node/7 = 8t+n
            #pragma unroll
            for (int r = 0; r < 4; ++r) {
                float z  = acc[r] + bb[nt];            // C/D: row=4lq+r, col=lm
                float sg = __builtin_amdgcn_rcpf(1.0f + __expf(-z));
                *(_Float16*)(qcur + (4 * lq + r) * RSTR + col * 2) = (_Float16)sg;
            }
        }

        // ---- Phase B: leaf probabilities (wave-lockstep, reads before writes) ----
        {
            const char* rowp = qcur + rg * RSTR;
            float sgv[4][7];
            #pragma unroll
            for (int tt = 0; tt < 4; ++tt) {
                int t = 4 * g + tt;                    // t=15 reads z=0 cols (0.5)
                #pragma unroll
                for (int n = 0; n < 7; ++n)
                    sgv[tt][n] = (float)*(const _Float16*)(rowp + (8 * t + n) * 2);
            }
            half8 lv[4];
            #pragma unroll
            for (int tt = 0; tt < 4; ++tt) {
                float s0 = sgv[tt][0], s1 = sgv[tt][1], s2 = sgv[tt][2];
                float s3 = sgv[tt][3], s4 = sgv[tt][4], s5 = sgv[tt][5], s6 = sgv[tt][6];
                float u1 = 1.f - s0, u2 = s0;
                float q1 = u1 * s1, q0 = u1 - q1;
                float q3 = u2 * s2, q2 = u2 - q3;
                float L1 = q0 * s3, L0 = q0 - L1;
                float L3 = q1 * s4, L2 = q1 - L3;
                float L5 = q2 * s5, L4 = q2 - L5;
                float L7 = q3 * s6, L6 = q3 - L7;
                float m = (4 * g + tt < TREES) ? 1.f : 0.f;   // zero tree-15 slot
                half8 lv8;
                lv8[0] = (_Float16)(L0 * m); lv8[1] = (_Float16)(L1 * m);
                lv8[2] = (_Float16)(L2 * m); lv8[3] = (_Float16)(L3 * m);
                lv8[4] = (_Float16)(L4 * m); lv8[5] = (_Float16)(L5 * m);
                lv8[6] = (_Float16)(L6 * m); lv8[7] = (_Float16)(L7 * m);
                lv[tt] = lv8;
            }
            #pragma unroll
            for (int tt = 0; tt < 4; ++tt)
                *(half8*)(qcur + rg * RSTR + 64 * g + 16 * tt) = lv[tt];
        }

        // ---- Phase C: leaf x wbT MFMA -> out ----
        {
            half8 af2[4];
            #pragma unroll
            for (int s = 0; s < 4; ++s)
                af2[s] = *(const half8*)(qcur + lm * RSTR + 64 * s + 16 * lq);
            f32x4 a2 = {0.f, 0.f, 0.f, 0.f};
            #pragma unroll
            for (int s = 0; s < 4; ++s)
                a2 = __builtin_amdgcn_mfma_f32_16x16x32_f16(af2[s], wbf[s], a2, 0, 0, 0);
            if (lm < NCLS) {
                #pragma unroll
                for (int r = 0; r < 4; ++r)
                    out[(grow + 16 * w + 4 * lq + r) * NCLS + lm] = a2[r];
            }
        }
    }
}

// ---------------------------------------------------------------------------
extern "C" void kernel_launch(void* const* d_in, const int* in_sizes, int n_in,
                              void* d_out, int out_size, void* d_ws, size_t ws_size,
                              hipStream_t stream) {
    const float* x      = (const float*)d_in[0];
    const float* params = (const float*)d_in[1];
    float* out = (float*)d_out;

    _Float16* wq  = (_Float16*)d_ws;                             // 28672 B
    float*    bq  = (float*)((char*)d_ws + NPAD * IDIM * 2);     // 448 B
    _Float16* wbT = (_Float16*)((char*)bq + NPAD * 4);           // 4096 B

    const int batch = in_sizes[0] / IDIM;      // 262144
    const int tiles = batch / 64;              // 4096
    const int tpb   = tiles / NBLK;            // 8

    prep_kernel<<<8, 256, 0, stream>>>(params, wq, bq, wbT);
    tree_main<<<NBLK, 256, 0, stream>>>(x, wq, bq, wbT, out, tpb);
}